// Round 3
// baseline (223.666 us; speedup 1.0000x reference)
//
#include <hip/hip_runtime.h>

// PaddedToSegments: batched stream compaction — fused; plain (cached) loads.
//   inputs: [B=16, T=2048, D=1024] f32
//   mask:   [B, T] bool (arrives as int32 per harness integer convention)
// Outputs flattened into one f32 buffer in return order:
//   collected [B,T,D] f32, valid_idx [B,T] (as float, -1 tail), counts [B] (as float)
//
// R2 post-mortem: scan amortization was neutral — kernel slice is BW-flat.
// This round tests the last real mechanism: __builtin_nontemporal_load on the
// gather stream bypasses L2 (MTYPE-uncached), and L2 is what coalesces lane
// requests into full HBM bursts. Switch loads to plain cached loads; keep NT
// stores (write stream must not pollute L2). Also: one row per wave-pair ->
// 64-lane x 16 B = 1 KB contiguous per load instruction, and the `c < cnt`
// branch becomes wave-uniform.

#define BB 16
#define TT 2048
#define DD 1024
#define ROW4 (DD / 4)    // 256 float4 per row
#define ROWS 16          // output rows per block
#define BPS (TT / ROWS)  // 128 blocks per sample

typedef float f4 __attribute__((ext_vector_type(4)));

__global__ __launch_bounds__(256) void fused_kernel(
    const int* __restrict__ mask,
    const f4* __restrict__ in,      // [B*T][256] f4
    f4* __restrict__ out,           // [B*T][256] f4
    float* __restrict__ out_vidx,   // [B,T] as float
    float* __restrict__ out_counts) // [B]   as float
{
    const int b    = blockIdx.x >> 7;        // 128 blocks per sample
    const int blk  = blockIdx.x & (BPS - 1);
    const int tid  = threadIdx.x;
    const int lane = tid & 63;
    const int wv   = tid >> 6;               // wave 0..3

    // ---- mask load: 8 values/thread (2x int4); row is 8 KB, L2-hot ----
    const int4* m4 = (const int4*)(mask + b * TT);
    int4 a0 = m4[tid * 2];
    int4 a1 = m4[tid * 2 + 1];
    int vals[8];
    vals[0] = (a0.x != 0); vals[1] = (a0.y != 0);
    vals[2] = (a0.z != 0); vals[3] = (a0.w != 0);
    vals[4] = (a1.x != 0); vals[5] = (a1.y != 0);
    vals[6] = (a1.z != 0); vals[7] = (a1.w != 0);
    int s = 0;
#pragma unroll
    for (int i = 0; i < 8; ++i) s += vals[i];

    // ---- block count: wave butterfly reduce + 4-entry combine ----
    int r = s;
#pragma unroll
    for (int off = 1; off < 64; off <<= 1) r += __shfl_xor(r, off, 64);

    __shared__ int wsum[4];
    __shared__ int ssrc[TT];   // compacted source row index, 8 KB
    if (lane == 0) wsum[wv] = r;
    __syncthreads();
    const int cnt = wsum[0] + wsum[1] + wsum[2] + wsum[3];

    const int row0 = blk * ROWS;

    // ---- scan + scatter only when this block owns valid rows (block-uniform) ----
    if (row0 < cnt || blk == 0) {
        int incl = s;
#pragma unroll
        for (int off = 1; off < 64; off <<= 1) {
            int v = __shfl_up(incl, off, 64);
            if (lane >= off) incl += v;
        }
        int woff = 0;
#pragma unroll
        for (int w = 0; w < 4; ++w) woff += (w < wv) ? wsum[w] : 0;
        int pos = woff + incl - s;   // exclusive prefix for this thread
#pragma unroll
        for (int i = 0; i < 8; ++i) {
            if (vals[i]) ssrc[pos++] = tid * 8 + i;
        }
        __syncthreads();
    }

    // ---- one designated block per sample emits valid_idx + counts ----
    if (blk == 0) {
        for (int c = tid; c < TT; c += 256)
            out_vidx[b * TT + c] = (c < cnt) ? (float)ssrc[c] : -1.0f;
        if (tid == 0) out_counts[b] = (float)cnt;
    }

    // ---- gather / zero-fill: each wave owns 4 rows (2 passes x 2 rows).
    //      One load inst = 64 lanes x 16 B = 1 KB contiguous; 4 insts/row;
    //      2 rows in flight -> 8 outstanding loads. `c < cnt` is wave-uniform. ----
#pragma unroll
    for (int p = 0; p < 2; ++p) {
        const int c0 = row0 + wv * 4 + p * 2;   // first of 2 rows this pass
        f4 v[8];
        const f4 z = {0.f, 0.f, 0.f, 0.f};

        if (c0 < cnt) {
            const f4* sp0 = in + ((size_t)(b * TT + ssrc[c0])) * ROW4;
#pragma unroll
            for (int j = 0; j < 4; ++j) v[j] = sp0[lane + j * 64];
        } else {
#pragma unroll
            for (int j = 0; j < 4; ++j) v[j] = z;
        }
        if (c0 + 1 < cnt) {
            const f4* sp1 = in + ((size_t)(b * TT + ssrc[c0 + 1])) * ROW4;
#pragma unroll
            for (int j = 0; j < 4; ++j) v[4 + j] = sp1[lane + j * 64];
        } else {
#pragma unroll
            for (int j = 0; j < 4; ++j) v[4 + j] = z;
        }

        f4* dst0 = out + ((size_t)(b * TT + c0)) * ROW4;
        f4* dst1 = dst0 + ROW4;
#pragma unroll
        for (int j = 0; j < 4; ++j)
            __builtin_nontemporal_store(v[j], dst0 + lane + j * 64);
#pragma unroll
        for (int j = 0; j < 4; ++j)
            __builtin_nontemporal_store(v[4 + j], dst1 + lane + j * 64);
    }
}

extern "C" void kernel_launch(void* const* d_in, const int* in_sizes, int n_in,
                              void* d_out, int out_size, void* d_ws, size_t ws_size,
                              hipStream_t stream) {
    const float* inputs = (const float*)d_in[0];
    const int* mask = (const int*)d_in[1];

    float* out = (float*)d_out;
    float* out_collected = out;                       // B*T*D
    float* out_vidx = out + (size_t)BB * TT * DD;     // B*T
    float* out_counts = out_vidx + (size_t)BB * TT;   // B

    fused_kernel<<<BB * BPS, 256, 0, stream>>>(
        mask, (const f4*)inputs, (f4*)out_collected, out_vidx, out_counts);
}